// Round 1
// baseline (771.662 us; speedup 1.0000x reference)
//
#include <hip/hip_runtime.h>
#include <hip/hip_bf16.h>
#include <cstdint>

#define AS1 __attribute__((address_space(1)))
#define AS3 __attribute__((address_space(3)))

typedef __attribute__((ext_vector_type(8))) __bf16 bf16x8;
typedef __attribute__((ext_vector_type(4))) float f32x4;

__device__ inline unsigned short f2bf(float f) {
    unsigned u = __float_as_uint(f);
    u += 0x7fffu + ((u >> 16) & 1);           // round-to-nearest-even
    return (unsigned short)(u >> 16);
}
__device__ inline float bf_lo(unsigned u) { return __uint_as_float(u << 16); }
__device__ inline float bf_hi(unsigned u) { return __uint_as_float(u & 0xffff0000u); }

// ---------------- fp32 -> bf16 cast (8 elems/thread) ----------------
__global__ void cast_f32_bf16(const float* __restrict__ src,
                              unsigned short* __restrict__ dst, int n) {
    int i = (blockIdx.x * blockDim.x + threadIdx.x) * 8;
    if (i >= n) return;
    float4 a = *(const float4*)(src + i);
    float4 b = *(const float4*)(src + i + 4);
    ushort4 lo, hi;
    lo.x = f2bf(a.x); lo.y = f2bf(a.y); lo.z = f2bf(a.z); lo.w = f2bf(a.w);
    hi.x = f2bf(b.x); hi.y = f2bf(b.y); hi.z = f2bf(b.z); hi.w = f2bf(b.w);
    *(ushort4*)(dst + i) = lo;
    *(ushort4*)(dst + i + 4) = hi;
}

// ---------------- bf16 GEMM, C[m,n] = scale * sum_k A[m,k]*B[n,k] ----------------
// 128x128 tile, BK=32, 256 thr (4 waves, 2x2), 16x16x32 MFMA, 4x4 tiles/wave.
// OUTF=0 -> bf16 output, OUTF=1 -> fp32 output.
template <int OUTF>
__global__ __launch_bounds__(256, 2)
void gemm_bt(const unsigned short* __restrict__ A, const unsigned short* __restrict__ B,
             void* __restrict__ Cv, int M, int N, int K, float scale) {
    __shared__ __align__(16) unsigned short As[128 * 32];
    __shared__ __align__(16) unsigned short Bs[128 * 32];

    const int t = threadIdx.x;
    const int w = t >> 6, lane = t & 63;
    const int bx = blockIdx.x, by = blockIdx.y;     // n-tile, m-tile
    const int wr = w >> 1, wc = w & 1;
    const int quad = lane >> 4, lr = lane & 15;

    f32x4 acc[4][4] = {};

    const unsigned short* gA = A + (size_t)(by * 128 + (t >> 2)) * K + (t & 3) * 8;
    const unsigned short* gB = B + (size_t)(bx * 128 + (t >> 2)) * K + (t & 3) * 8;
    char* aBase = (char*)As + w * 1024;             // wave-uniform LDS dst
    char* bBase = (char*)Bs + w * 1024;

    for (int k0 = 0; k0 < K; k0 += 32) {
        __builtin_amdgcn_global_load_lds((const AS1 void*)gA,
                                         (AS3 void*)aBase, 16, 0, 0);
        __builtin_amdgcn_global_load_lds((const AS1 void*)(gA + (size_t)64 * K),
                                         (AS3 void*)(aBase + 4096), 16, 0, 0);
        __builtin_amdgcn_global_load_lds((const AS1 void*)gB,
                                         (AS3 void*)bBase, 16, 0, 0);
        __builtin_amdgcn_global_load_lds((const AS1 void*)(gB + (size_t)64 * K),
                                         (AS3 void*)(bBase + 4096), 16, 0, 0);
        gA += 32; gB += 32;
        __syncthreads();

        bf16x8 af[4], bfr[4];
#pragma unroll
        for (int i = 0; i < 4; i++)
            af[i] = *(const bf16x8*)(As + (wr * 64 + i * 16 + lr) * 32 + quad * 8);
#pragma unroll
        for (int j = 0; j < 4; j++)
            bfr[j] = *(const bf16x8*)(Bs + (wc * 64 + j * 16 + lr) * 32 + quad * 8);
#pragma unroll
        for (int i = 0; i < 4; i++)
#pragma unroll
            for (int j = 0; j < 4; j++)
                acc[i][j] = __builtin_amdgcn_mfma_f32_16x16x32_bf16(
                    af[i], bfr[j], acc[i][j], 0, 0, 0);
        __syncthreads();
    }

#pragma unroll
    for (int i = 0; i < 4; i++) {
        int row0 = by * 128 + wr * 64 + i * 16 + quad * 4;
#pragma unroll
        for (int j = 0; j < 4; j++) {
            int col = bx * 128 + wc * 64 + j * 16 + lr;
#pragma unroll
            for (int r = 0; r < 4; r++) {
                float vv = acc[i][j][r] * scale;
                size_t idx = (size_t)(row0 + r) * N + col;
                if (OUTF) ((float*)Cv)[idx] = vv;
                else      ((unsigned short*)Cv)[idx] = f2bf(vv);
            }
        }
    }
}

// ---------------- fused neighbor attention ----------------
// one wave per (b,s,kv); block = 4 waves; grid = BS*2 (kv quads)
// q: [BS, 2048] bf16 (scaler pre-applied), k/v: [BS*16, 512] bf16,
// out: [BS, 2048] bf16.  G=4 heads/group, N=16 neighbors, HD=64.
__global__ __launch_bounds__(256, 4)
void attn_kernel(const unsigned short* __restrict__ q,
                 const unsigned short* __restrict__ k,
                 const unsigned short* __restrict__ v,
                 unsigned short* __restrict__ ao) {
    __shared__ __align__(16) unsigned short qs[4][4][72];
    __shared__ __align__(16) unsigned short ks[4][16][72];
    __shared__ __align__(16) unsigned short vs[4][16][72];
    __shared__ float ps[4][4][17];

    const int t = threadIdx.x, w = t >> 6, lane = t & 63;
    const int bs = blockIdx.x >> 1;
    const int kv = (blockIdx.x & 1) * 4 + w;

    // stage q: 256 bf16 = 512 B contiguous
    if (lane < 32) {
        int g = lane >> 3, part = lane & 7;
        *(int4*)(&qs[w][g][part * 8]) =
            *(const int4*)(q + (size_t)bs * 2048 + kv * 256 + lane * 8);
    }
    // stage k/v: 16 rows x 128 B
#pragma unroll
    for (int p = 0; p < 2; p++) {
        int n = p * 8 + (lane >> 3), part = lane & 7;
        size_t src = ((size_t)bs * 16 + n) * 512 + kv * 64 + part * 8;
        *(int4*)(&ks[w][n][part * 8]) = *(const int4*)(k + src);
        *(int4*)(&vs[w][n][part * 8]) = *(const int4*)(v + src);
    }
    __syncthreads();

    // scores + softmax: lane -> (g = lane&3, n = lane>>2)
    {
        const int g = lane & 3, n = lane >> 2;
        const unsigned short* qr = qs[w][g];
        const unsigned short* kr = ks[w][n];
        float s = 0.f;
#pragma unroll
        for (int d = 0; d < 64; d += 2) {
            unsigned uq = *(const unsigned*)(qr + d);
            unsigned uk = *(const unsigned*)(kr + d);
            s += bf_lo(uq) * bf_lo(uk) + bf_hi(uq) * bf_hi(uk);
        }
        float m = s;
#pragma unroll
        for (int off = 4; off < 64; off <<= 1) m = fmaxf(m, __shfl_xor(m, off));
        float e = __expf(s - m);
        float sum = e;
#pragma unroll
        for (int off = 4; off < 64; off <<= 1) sum += __shfl_xor(sum, off);
        ps[w][g][n] = e / sum;
    }
    __syncthreads();

    // PV: lane -> (g = lane&3, d0 = (lane>>2)*4)
    {
        const int g = lane & 3, d0 = (lane >> 2) * 4;
        float o0 = 0, o1 = 0, o2 = 0, o3 = 0;
#pragma unroll
        for (int n = 0; n < 16; n++) {
            float pv = ps[w][g][n];
            unsigned u0 = *(const unsigned*)(&vs[w][n][d0]);
            unsigned u1 = *(const unsigned*)(&vs[w][n][d0 + 2]);
            o0 += pv * bf_lo(u0); o1 += pv * bf_hi(u0);
            o2 += pv * bf_lo(u1); o3 += pv * bf_hi(u1);
        }
        unsigned r0 = ((unsigned)f2bf(o1) << 16) | f2bf(o0);
        unsigned r1 = ((unsigned)f2bf(o3) << 16) | f2bf(o2);
        uint2 rr = make_uint2(r0, r1);
        *(uint2*)(ao + (size_t)bs * 2048 + kv * 256 + g * 64 + d0) = rr;
    }
}

extern "C" void kernel_launch(void* const* d_in, const int* in_sizes, int n_in,
                              void* d_out, int out_size, void* d_ws, size_t ws_size,
                              hipStream_t stream) {
    (void)in_sizes; (void)n_in; (void)out_size; (void)ws_size;
    const float* hs = (const float*)d_in[0];
    const float* rh = (const float*)d_in[1];
    const float* Wq = (const float*)d_in[2];
    const float* Wk = (const float*)d_in[3];
    const float* Wv = (const float*)d_in[4];
    const float* Wo = (const float*)d_in[5];
    float* out = (float*)d_out;

    const int BS = 4096;            // B*S
    const int H = 2048, RH = 1024, KVD = 512, NN = 16;

    char* ws = (char*)d_ws;
    auto alloc = [&](size_t elems) {
        unsigned short* p = (unsigned short*)ws;
        ws += elems * 2;
        return p;
    };
    unsigned short* hs_b = alloc((size_t)BS * H);          // 16.8 MB
    unsigned short* rh_b = alloc((size_t)BS * NN * RH);    // 134 MB
    unsigned short* wq_b = alloc((size_t)H * H);           // 8.4 MB
    unsigned short* wk_b = alloc((size_t)KVD * RH);        // 1 MB
    unsigned short* wv_b = alloc((size_t)KVD * RH);        // 1 MB
    unsigned short* wo_b = alloc((size_t)H * H);           // 8.4 MB
    unsigned short* q_b  = alloc((size_t)BS * H);          // 16.8 MB
    unsigned short* k_b  = alloc((size_t)BS * NN * KVD);   // 67 MB
    unsigned short* v_b  = alloc((size_t)BS * NN * KVD);   // 67 MB
    unsigned short* ao_b = hs_b;   // reuse: hs_b dead after Q-GEMM

    auto cast = [&](const float* s, unsigned short* d, int n) {
        cast_f32_bf16<<<n / 2048, 256, 0, stream>>>(s, d, n);
    };
    cast(hs, hs_b, BS * H);
    cast(rh, rh_b, BS * NN * RH);
    cast(Wq, wq_b, H * H);
    cast(Wk, wk_b, KVD * RH);
    cast(Wv, wv_b, KVD * RH);
    cast(Wo, wo_b, H * H);

    // q = (hs @ Wq^T) * HD^-0.5
    gemm_bt<0><<<dim3(H / 128, BS / 128), 256, 0, stream>>>(
        hs_b, wq_b, q_b, BS, H, H, 0.125f);
    // k/v = retrieved @ W{k,v}^T
    gemm_bt<0><<<dim3(KVD / 128, (BS * NN) / 128), 256, 0, stream>>>(
        rh_b, wk_b, k_b, BS * NN, KVD, RH, 1.0f);
    gemm_bt<0><<<dim3(KVD / 128, (BS * NN) / 128), 256, 0, stream>>>(
        rh_b, wv_b, v_b, BS * NN, KVD, RH, 1.0f);
    // fused per-position attention
    attn_kernel<<<BS * 2, 256, 0, stream>>>(q_b, k_b, v_b, ao_b);
    // final projection -> fp32 output
    gemm_bt<1><<<dim3(H / 128, BS / 128), 256, 0, stream>>>(
        ao_b, wo_b, out, BS, H, H, 1.0f);
}

// Round 2
// 758.847 us; speedup vs baseline: 1.0169x; 1.0169x over previous
//
#include <hip/hip_runtime.h>
#include <hip/hip_bf16.h>
#include <cstdint>

#define AS1 __attribute__((address_space(1)))
#define AS3 __attribute__((address_space(3)))

typedef __attribute__((ext_vector_type(8))) __bf16 bf16x8;
typedef __attribute__((ext_vector_type(4))) float f32x4;

__device__ inline unsigned short f2bf(float f) {
    unsigned u = __float_as_uint(f);
    u += 0x7fffu + ((u >> 16) & 1);           // round-to-nearest-even
    return (unsigned short)(u >> 16);
}
__device__ inline float bf_lo(unsigned u) { return __uint_as_float(u << 16); }
__device__ inline float bf_hi(unsigned u) { return __uint_as_float(u & 0xffff0000u); }

// ---------------- fused fp32 -> bf16 cast over all 6 inputs ----------------
struct CastArgs {
    const float* s[6];
    unsigned short* d[6];
    long end[6];        // exclusive prefix ends (elements), multiples of 8
};

__global__ void cast_all(CastArgs a, long total) {
    long e = ((long)blockIdx.x * blockDim.x + threadIdx.x) * 8;
    if (e >= total) return;
    int seg = 0;
#pragma unroll
    for (int i = 0; i < 5; i++) seg += (e >= a.end[seg]) ? 1 : 0;
    long base = seg ? a.end[seg - 1] : 0;
    long local = e - base;
    const float* src = a.s[seg] + local;
    float4 x = *(const float4*)src;
    float4 y = *(const float4*)(src + 4);
    ushort4 lo, hi;
    lo.x = f2bf(x.x); lo.y = f2bf(x.y); lo.z = f2bf(x.z); lo.w = f2bf(x.w);
    hi.x = f2bf(y.x); hi.y = f2bf(y.y); hi.z = f2bf(y.z); hi.w = f2bf(y.w);
    unsigned short* dst = a.d[seg] + local;
    *(ushort4*)dst = lo;
    *(ushort4*)(dst + 4) = hi;
}

// ---------------- bf16 GEMM, C[m,n] = scale * sum_k A[m,k]*B[n,k] ----------------
// 128x128 tile, BK=32, 256 thr (4 waves, 2x2), 16x16x32 MFMA, 4x4 tiles/wave.
// OUTF=0 -> bf16 output, OUTF=1 -> fp32 output.
template <int OUTF>
__global__ __launch_bounds__(256, 2)
void gemm_bt(const unsigned short* __restrict__ A, const unsigned short* __restrict__ B,
             void* __restrict__ Cv, int M, int N, int K, float scale) {
    __shared__ __align__(16) unsigned short As[128 * 32];
    __shared__ __align__(16) unsigned short Bs[128 * 32];

    const int t = threadIdx.x;
    const int w = t >> 6, lane = t & 63;
    const int bx = blockIdx.x, by = blockIdx.y;     // n-tile, m-tile
    const int wr = w >> 1, wc = w & 1;
    const int quad = lane >> 4, lr = lane & 15;

    f32x4 acc[4][4] = {};

    const unsigned short* gA = A + (size_t)(by * 128 + (t >> 2)) * K + (t & 3) * 8;
    const unsigned short* gB = B + (size_t)(bx * 128 + (t >> 2)) * K + (t & 3) * 8;
    char* aBase = (char*)As + w * 1024;             // wave-uniform LDS dst
    char* bBase = (char*)Bs + w * 1024;

    for (int k0 = 0; k0 < K; k0 += 32) {
        __builtin_amdgcn_global_load_lds((const AS1 void*)gA,
                                         (AS3 void*)aBase, 16, 0, 0);
        __builtin_amdgcn_global_load_lds((const AS1 void*)(gA + (size_t)64 * K),
                                         (AS3 void*)(aBase + 4096), 16, 0, 0);
        __builtin_amdgcn_global_load_lds((const AS1 void*)gB,
                                         (AS3 void*)bBase, 16, 0, 0);
        __builtin_amdgcn_global_load_lds((const AS1 void*)(gB + (size_t)64 * K),
                                         (AS3 void*)(bBase + 4096), 16, 0, 0);
        gA += 32; gB += 32;
        __syncthreads();

        bf16x8 af[4], bfr[4];
#pragma unroll
        for (int i = 0; i < 4; i++)
            af[i] = *(const bf16x8*)(As + (wr * 64 + i * 16 + lr) * 32 + quad * 8);
#pragma unroll
        for (int j = 0; j < 4; j++)
            bfr[j] = *(const bf16x8*)(Bs + (wc * 64 + j * 16 + lr) * 32 + quad * 8);
#pragma unroll
        for (int i = 0; i < 4; i++)
#pragma unroll
            for (int j = 0; j < 4; j++)
                acc[i][j] = __builtin_amdgcn_mfma_f32_16x16x32_bf16(
                    af[i], bfr[j], acc[i][j], 0, 0, 0);
        __syncthreads();
    }

#pragma unroll
    for (int i = 0; i < 4; i++) {
        int row0 = by * 128 + wr * 64 + i * 16 + quad * 4;
#pragma unroll
        for (int j = 0; j < 4; j++) {
            int col = bx * 128 + wc * 64 + j * 16 + lr;
#pragma unroll
            for (int r = 0; r < 4; r++) {
                float vv = acc[i][j][r] * scale;
                size_t idx = (size_t)(row0 + r) * N + col;
                if (OUTF) ((float*)Cv)[idx] = vv;
                else      ((unsigned short*)Cv)[idx] = f2bf(vv);
            }
        }
    }
}

// ---------------- fused neighbor attention ----------------
// one wave per (b,s,kv); block = 4 waves; grid = BS*2 (kv quads)
// q: [BS, 2048] bf16 (scaler pre-applied)
// kv: [BS*16, 1024] bf16 -- cols [0,512) = K, [512,1024) = V
// out: [BS, 2048] bf16.  G=4 heads/group, N=16 neighbors, HD=64.
__global__ __launch_bounds__(256, 4)
void attn_kernel(const unsigned short* __restrict__ q,
                 const unsigned short* __restrict__ kvb,
                 unsigned short* __restrict__ ao) {
    __shared__ __align__(16) unsigned short qs[4][4][72];
    __shared__ __align__(16) unsigned short ks[4][16][72];
    __shared__ __align__(16) unsigned short vs[4][16][72];
    __shared__ float ps[4][4][17];

    const int t = threadIdx.x, w = t >> 6, lane = t & 63;
    const int bs = blockIdx.x >> 1;
    const int kv = (blockIdx.x & 1) * 4 + w;

    // stage q: 256 bf16 = 512 B contiguous
    if (lane < 32) {
        int g = lane >> 3, part = lane & 7;
        *(int4*)(&qs[w][g][part * 8]) =
            *(const int4*)(q + (size_t)bs * 2048 + kv * 256 + lane * 8);
    }
    // stage k/v: 16 rows x 128 B each
#pragma unroll
    for (int p = 0; p < 2; p++) {
        int n = p * 8 + (lane >> 3), part = lane & 7;
        size_t src = ((size_t)bs * 16 + n) * 1024 + kv * 64 + part * 8;
        *(int4*)(&ks[w][n][part * 8]) = *(const int4*)(kvb + src);
        *(int4*)(&vs[w][n][part * 8]) = *(const int4*)(kvb + src + 512);
    }
    __syncthreads();

    // scores + softmax: lane -> (g = lane&3, n = lane>>2)
    {
        const int g = lane & 3, n = lane >> 2;
        const unsigned short* qr = qs[w][g];
        const unsigned short* kr = ks[w][n];
        float s = 0.f;
#pragma unroll
        for (int d = 0; d < 64; d += 2) {
            unsigned uq = *(const unsigned*)(qr + d);
            unsigned uk = *(const unsigned*)(kr + d);
            s += bf_lo(uq) * bf_lo(uk) + bf_hi(uq) * bf_hi(uk);
        }
        float m = s;
#pragma unroll
        for (int off = 4; off < 64; off <<= 1) m = fmaxf(m, __shfl_xor(m, off));
        float e = __expf(s - m);
        float sum = e;
#pragma unroll
        for (int off = 4; off < 64; off <<= 1) sum += __shfl_xor(sum, off);
        ps[w][g][n] = e / sum;
    }
    __syncthreads();

    // PV: lane -> (g = lane&3, d0 = (lane>>2)*4)
    {
        const int g = lane & 3, d0 = (lane >> 2) * 4;
        float o0 = 0, o1 = 0, o2 = 0, o3 = 0;
#pragma unroll
        for (int n = 0; n < 16; n++) {
            float pv = ps[w][g][n];
            unsigned u0 = *(const unsigned*)(&vs[w][n][d0]);
            unsigned u1 = *(const unsigned*)(&vs[w][n][d0 + 2]);
            o0 += pv * bf_lo(u0); o1 += pv * bf_hi(u0);
            o2 += pv * bf_lo(u1); o3 += pv * bf_hi(u1);
        }
        unsigned r0 = ((unsigned)f2bf(o1) << 16) | f2bf(o0);
        unsigned r1 = ((unsigned)f2bf(o3) << 16) | f2bf(o2);
        uint2 rr = make_uint2(r0, r1);
        *(uint2*)(ao + (size_t)bs * 2048 + kv * 256 + g * 64 + d0) = rr;
    }
}

extern "C" void kernel_launch(void* const* d_in, const int* in_sizes, int n_in,
                              void* d_out, int out_size, void* d_ws, size_t ws_size,
                              hipStream_t stream) {
    (void)in_sizes; (void)n_in; (void)out_size; (void)ws_size;
    const float* hs = (const float*)d_in[0];
    const float* rh = (const float*)d_in[1];
    const float* Wq = (const float*)d_in[2];
    const float* Wk = (const float*)d_in[3];
    const float* Wv = (const float*)d_in[4];
    const float* Wo = (const float*)d_in[5];
    float* out = (float*)d_out;

    const int BS = 4096;            // B*S
    const int H = 2048, RH = 1024, KVD = 512, NN = 16;

    char* ws = (char*)d_ws;
    auto alloc = [&](size_t elems) {
        unsigned short* p = (unsigned short*)ws;
        ws += elems * 2;
        return p;
    };
    unsigned short* hs_b = alloc((size_t)BS * H);          // 16.8 MB
    unsigned short* rh_b = alloc((size_t)BS * NN * RH);    // 134 MB
    unsigned short* wq_b = alloc((size_t)H * H);           // 8.4 MB
    unsigned short* wk_b = alloc((size_t)KVD * RH);        // 1 MB  -- contiguous with
    unsigned short* wv_b = alloc((size_t)KVD * RH);        // 1 MB  -- wk_b: stacked Wkv [1024,1024]
    unsigned short* wo_b = alloc((size_t)H * H);           // 8.4 MB
    unsigned short* q_b  = alloc((size_t)BS * H);          // 16.8 MB
    unsigned short* kv_b = alloc((size_t)BS * NN * 2 * KVD); // 134 MB  (K | V per row)
    unsigned short* ao_b = hs_b;   // reuse: hs_b dead after Q-GEMM
    (void)wv_b;

    // single fused cast of all 6 fp32 inputs -> bf16
    CastArgs ca;
    ca.s[0] = hs;  ca.d[0] = hs_b;
    ca.s[1] = rh;  ca.d[1] = rh_b;
    ca.s[2] = Wq;  ca.d[2] = wq_b;
    ca.s[3] = Wk;  ca.d[3] = wk_b;
    ca.s[4] = Wv;  ca.d[4] = wv_b;
    ca.s[5] = Wo;  ca.d[5] = wo_b;
    long sizes[6] = {(long)BS * H, (long)BS * NN * RH, (long)H * H,
                     (long)KVD * RH, (long)KVD * RH, (long)H * H};
    long acc = 0;
    for (int i = 0; i < 6; i++) { acc += sizes[i]; ca.end[i] = acc; }
    long total = acc;
    int cast_blocks = (int)((total / 8 + 255) / 256);
    cast_all<<<cast_blocks, 256, 0, stream>>>(ca, total);

    // q = (hs @ Wq^T) * HD^-0.5
    gemm_bt<0><<<dim3(H / 128, BS / 128), 256, 0, stream>>>(
        hs_b, wq_b, q_b, BS, H, H, 0.125f);
    // kv = retrieved @ [Wk;Wv]^T   (single fused GEMM, A read once)
    gemm_bt<0><<<dim3((2 * KVD) / 128, (BS * NN) / 128), 256, 0, stream>>>(
        rh_b, wk_b, kv_b, BS * NN, 2 * KVD, RH, 1.0f);
    // fused per-position attention
    attn_kernel<<<BS * 2, 256, 0, stream>>>(q_b, kv_b, ao_b);
    // final projection -> fp32 output
    gemm_bt<1><<<dim3(H / 128, BS / 128), 256, 0, stream>>>(
        ao_b, wo_b, out, BS, H, H, 1.0f);
}

// Round 3
// 754.900 us; speedup vs baseline: 1.0222x; 1.0052x over previous
//
#include <hip/hip_runtime.h>
#include <hip/hip_bf16.h>
#include <cstdint>

#define AS1 __attribute__((address_space(1)))
#define AS3 __attribute__((address_space(3)))

typedef __attribute__((ext_vector_type(8))) __bf16 bf16x8;
typedef __attribute__((ext_vector_type(4))) float f32x4;

__device__ inline unsigned short f2bf(float f) {
    unsigned u = __float_as_uint(f);
    u += 0x7fffu + ((u >> 16) & 1);           // round-to-nearest-even
    return (unsigned short)(u >> 16);
}
__device__ inline float bf_lo(unsigned u) { return __uint_as_float(u << 16); }
__device__ inline float bf_hi(unsigned u) { return __uint_as_float(u & 0xffff0000u); }

// ---------------- fused fp32 -> bf16 cast over all 6 inputs ----------------
struct CastArgs {
    const float* s[6];
    unsigned short* d[6];
    long end[6];        // exclusive prefix ends (elements), multiples of 8
};

__global__ void cast_all(CastArgs a, long total) {
    long e = ((long)blockIdx.x * blockDim.x + threadIdx.x) * 8;
    if (e >= total) return;
    int seg = 0;
#pragma unroll
    for (int i = 0; i < 5; i++) seg += (e >= a.end[seg]) ? 1 : 0;
    long base = seg ? a.end[seg - 1] : 0;
    long local = e - base;
    const float* src = a.s[seg] + local;
    float4 x = *(const float4*)src;
    float4 y = *(const float4*)(src + 4);
    ushort4 lo, hi;
    lo.x = f2bf(x.x); lo.y = f2bf(x.y); lo.z = f2bf(x.z); lo.w = f2bf(x.w);
    hi.x = f2bf(y.x); hi.y = f2bf(y.y); hi.z = f2bf(y.z); hi.w = f2bf(y.w);
    unsigned short* dst = a.d[seg] + local;
    *(ushort4*)dst = lo;
    *(ushort4*)(dst + 4) = hi;
}

// ---------------- bf16 GEMM, C[m,n] = scale * sum_k A[m,k]*B[n,k] ----------------
// 128x128 tile, BK=32, 256 thr (4 waves, 2x2), 16x16x32 MFMA, 4x4 tiles/wave.
// LDS chunk-XOR swizzle: global 16B-chunk g of row r lives at LDS chunk
// g ^ ((r>>1)&3).  Staging applies the XOR on the global source address
// (global_load_lds is lane-linear in LDS); fragment reads XOR the same term.
// Makes every 8-lane phase group of ds_read_b128 hit all 32 banks once.
// OUTF=0 -> bf16 output, OUTF=1 -> fp32 output.
template <int OUTF>
__global__ __launch_bounds__(256, 2)
void gemm_bt(const unsigned short* __restrict__ A, const unsigned short* __restrict__ B,
             void* __restrict__ Cv, int M, int N, int K, float scale) {
    __shared__ __align__(16) unsigned short As[128 * 32];
    __shared__ __align__(16) unsigned short Bs[128 * 32];

    const int t = threadIdx.x;
    const int w = t >> 6, lane = t & 63;
    const int bx = blockIdx.x, by = blockIdx.y;     // n-tile, m-tile
    const int wr = w >> 1, wc = w & 1;
    const int quad = lane >> 4, lr = lane & 15;

    f32x4 acc[4][4] = {};

    // staging: thread t covers row t>>2, LDS chunk t&3; fetch global chunk
    // (t&3) ^ ((row>>1)&3).  Row+64 has the same swizzle term.
    const int srow = t >> 2;
    const int schunk = (t & 3) ^ ((srow >> 1) & 3);
    const unsigned short* gA = A + (size_t)(by * 128 + srow) * K + schunk * 8;
    const unsigned short* gB = B + (size_t)(bx * 128 + srow) * K + schunk * 8;
    char* aBase = (char*)As + w * 1024;             // wave-uniform LDS dst
    char* bBase = (char*)Bs + w * 1024;

    // fragment-read swizzle term (wave-uniform per lane)
    const int rsw = (lr >> 1) & 3;
    const int aoff = quad ^ rsw;                    // LDS chunk to read

    for (int k0 = 0; k0 < K; k0 += 32) {
        __builtin_amdgcn_global_load_lds((const AS1 void*)gA,
                                         (AS3 void*)aBase, 16, 0, 0);
        __builtin_amdgcn_global_load_lds((const AS1 void*)(gA + (size_t)64 * K),
                                         (AS3 void*)(aBase + 4096), 16, 0, 0);
        __builtin_amdgcn_global_load_lds((const AS1 void*)gB,
                                         (AS3 void*)bBase, 16, 0, 0);
        __builtin_amdgcn_global_load_lds((const AS1 void*)(gB + (size_t)64 * K),
                                         (AS3 void*)(bBase + 4096), 16, 0, 0);
        gA += 32; gB += 32;
        __syncthreads();

        bf16x8 af[4], bfr[4];
#pragma unroll
        for (int i = 0; i < 4; i++)
            af[i] = *(const bf16x8*)(As + (wr * 64 + i * 16 + lr) * 32 + aoff * 8);
#pragma unroll
        for (int j = 0; j < 4; j++)
            bfr[j] = *(const bf16x8*)(Bs + (wc * 64 + j * 16 + lr) * 32 + aoff * 8);
#pragma unroll
        for (int i = 0; i < 4; i++)
#pragma unroll
            for (int j = 0; j < 4; j++)
                acc[i][j] = __builtin_amdgcn_mfma_f32_16x16x32_bf16(
                    af[i], bfr[j], acc[i][j], 0, 0, 0);
        __syncthreads();
    }

#pragma unroll
    for (int i = 0; i < 4; i++) {
        int row0 = by * 128 + wr * 64 + i * 16 + quad * 4;
#pragma unroll
        for (int j = 0; j < 4; j++) {
            int col = bx * 128 + wc * 64 + j * 16 + lr;
#pragma unroll
            for (int r = 0; r < 4; r++) {
                float vv = acc[i][j][r] * scale;
                size_t idx = (size_t)(row0 + r) * N + col;
                if (OUTF) ((float*)Cv)[idx] = vv;
                else      ((unsigned short*)Cv)[idx] = f2bf(vv);
            }
        }
    }
}

// ---------------- fused neighbor attention ----------------
// one wave per (b,s,kv); block = 4 waves; grid = BS*2 (kv quads)
// q: [BS, 2048] bf16 (scaler pre-applied)
// kv: [BS*16, 1024] bf16 -- cols [0,512) = K, [512,1024) = V
// out: [BS, 2048] bf16.  G=4 heads/group, N=16 neighbors, HD=64.
__global__ __launch_bounds__(256, 4)
void attn_kernel(const unsigned short* __restrict__ q,
                 const unsigned short* __restrict__ kvb,
                 unsigned short* __restrict__ ao) {
    __shared__ __align__(16) unsigned short qs[4][4][72];
    __shared__ __align__(16) unsigned short ks[4][16][72];
    __shared__ __align__(16) unsigned short vs[4][16][72];
    __shared__ float ps[4][4][17];

    const int t = threadIdx.x, w = t >> 6, lane = t & 63;
    const int bs = blockIdx.x >> 1;
    const int kv = (blockIdx.x & 1) * 4 + w;

    // stage q: 256 bf16 = 512 B contiguous
    if (lane < 32) {
        int g = lane >> 3, part = lane & 7;
        *(int4*)(&qs[w][g][part * 8]) =
            *(const int4*)(q + (size_t)bs * 2048 + kv * 256 + lane * 8);
    }
    // stage k/v: 16 rows x 128 B each
#pragma unroll
    for (int p = 0; p < 2; p++) {
        int n = p * 8 + (lane >> 3), part = lane & 7;
        size_t src = ((size_t)bs * 16 + n) * 1024 + kv * 64 + part * 8;
        *(int4*)(&ks[w][n][part * 8]) = *(const int4*)(kvb + src);
        *(int4*)(&vs[w][n][part * 8]) = *(const int4*)(kvb + src + 512);
    }
    __syncthreads();

    // scores + softmax: lane -> (g = lane&3, n = lane>>2)
    {
        const int g = lane & 3, n = lane >> 2;
        const unsigned short* qr = qs[w][g];
        const unsigned short* kr = ks[w][n];
        float s = 0.f;
#pragma unroll
        for (int d = 0; d < 64; d += 2) {
            unsigned uq = *(const unsigned*)(qr + d);
            unsigned uk = *(const unsigned*)(kr + d);
            s += bf_lo(uq) * bf_lo(uk) + bf_hi(uq) * bf_hi(uk);
        }
        float m = s;
#pragma unroll
        for (int off = 4; off < 64; off <<= 1) m = fmaxf(m, __shfl_xor(m, off));
        float e = __expf(s - m);
        float sum = e;
#pragma unroll
        for (int off = 4; off < 64; off <<= 1) sum += __shfl_xor(sum, off);
        ps[w][g][n] = e / sum;
    }
    __syncthreads();

    // PV: lane -> (g = lane&3, d0 = (lane>>2)*4)
    {
        const int g = lane & 3, d0 = (lane >> 2) * 4;
        float o0 = 0, o1 = 0, o2 = 0, o3 = 0;
#pragma unroll
        for (int n = 0; n < 16; n++) {
            float pv = ps[w][g][n];
            unsigned u0 = *(const unsigned*)(&vs[w][n][d0]);
            unsigned u1 = *(const unsigned*)(&vs[w][n][d0 + 2]);
            o0 += pv * bf_lo(u0); o1 += pv * bf_hi(u0);
            o2 += pv * bf_lo(u1); o3 += pv * bf_hi(u1);
        }
        unsigned r0 = ((unsigned)f2bf(o1) << 16) | f2bf(o0);
        unsigned r1 = ((unsigned)f2bf(o3) << 16) | f2bf(o2);
        uint2 rr = make_uint2(r0, r1);
        *(uint2*)(ao + (size_t)bs * 2048 + kv * 256 + g * 64 + d0) = rr;
    }
}

extern "C" void kernel_launch(void* const* d_in, const int* in_sizes, int n_in,
                              void* d_out, int out_size, void* d_ws, size_t ws_size,
                              hipStream_t stream) {
    (void)in_sizes; (void)n_in; (void)out_size; (void)ws_size;
    const float* hs = (const float*)d_in[0];
    const float* rh = (const float*)d_in[1];
    const float* Wq = (const float*)d_in[2];
    const float* Wk = (const float*)d_in[3];
    const float* Wv = (const float*)d_in[4];
    const float* Wo = (const float*)d_in[5];
    float* out = (float*)d_out;

    const int BS = 4096;            // B*S
    const int H = 2048, RH = 1024, KVD = 512, NN = 16;

    char* ws = (char*)d_ws;
    auto alloc = [&](size_t elems) {
        unsigned short* p = (unsigned short*)ws;
        ws += elems * 2;
        return p;
    };
    unsigned short* hs_b = alloc((size_t)BS * H);          // 16.8 MB
    unsigned short* rh_b = alloc((size_t)BS * NN * RH);    // 134 MB
    unsigned short* wq_b = alloc((size_t)H * H);           // 8.4 MB
    unsigned short* wk_b = alloc((size_t)KVD * RH);        // 1 MB  -- contiguous with
    unsigned short* wv_b = alloc((size_t)KVD * RH);        // 1 MB  -- wk_b: stacked Wkv [1024,1024]
    unsigned short* wo_b = alloc((size_t)H * H);           // 8.4 MB
    unsigned short* q_b  = alloc((size_t)BS * H);          // 16.8 MB
    unsigned short* kv_b = alloc((size_t)BS * NN * 2 * KVD); // 134 MB  (K | V per row)
    unsigned short* ao_b = hs_b;   // reuse: hs_b dead after Q-GEMM
    (void)wv_b;

    // single fused cast of all 6 fp32 inputs -> bf16
    CastArgs ca;
    ca.s[0] = hs;  ca.d[0] = hs_b;
    ca.s[1] = rh;  ca.d[1] = rh_b;
    ca.s[2] = Wq;  ca.d[2] = wq_b;
    ca.s[3] = Wk;  ca.d[3] = wk_b;
    ca.s[4] = Wv;  ca.d[4] = wv_b;
    ca.s[5] = Wo;  ca.d[5] = wo_b;
    long sizes[6] = {(long)BS * H, (long)BS * NN * RH, (long)H * H,
                     (long)KVD * RH, (long)KVD * RH, (long)H * H};
    long acc = 0;
    for (int i = 0; i < 6; i++) { acc += sizes[i]; ca.end[i] = acc; }
    long total = acc;
    int cast_blocks = (int)((total / 8 + 255) / 256);
    cast_all<<<cast_blocks, 256, 0, stream>>>(ca, total);

    // q = (hs @ Wq^T) * HD^-0.5
    gemm_bt<0><<<dim3(H / 128, BS / 128), 256, 0, stream>>>(
        hs_b, wq_b, q_b, BS, H, H, 0.125f);
    // kv = retrieved @ [Wk;Wv]^T   (single fused GEMM, A read once)
    gemm_bt<0><<<dim3((2 * KVD) / 128, (BS * NN) / 128), 256, 0, stream>>>(
        rh_b, wk_b, kv_b, BS * NN, 2 * KVD, RH, 1.0f);
    // fused per-position attention
    attn_kernel<<<BS * 2, 256, 0, stream>>>(q_b, kv_b, ao_b);
    // final projection -> fp32 output
    gemm_bt<1><<<dim3(H / 128, BS / 128), 256, 0, stream>>>(
        ao_b, wo_b, out, BS, H, H, 1.0f);
}